// Round 1
// baseline (203.870 us; speedup 1.0000x reference)
//
#include <hip/hip_runtime.h>
#include <math.h>

// Problem constants: B=16, C=128, H=W=64 -> N = 8,388,608 f32 elements.
#define NTOT 8388608
#define NV   (NTOT / 4)   // float4 count = 2,097,152

// The entire reference collapses:
//   softmax(w).sum(axis=1) == 1  =>  integral(d, param, idx) == param[idx]
//   linspace tables are affine   =>  interplot == a + b*index
//   theta = -pi + 2*pi*sigmoid(d)
//   ds    = e * |tanh(d)|
//   pre   = d*exp(ds*sin(theta)) + ds*cos(theta)
// with global (mean, std ddof=1) normalization of input (x iscale) and of
// the pre-output (x oscale).

__device__ __forceinline__ float fast_rcp(float x) {
    return __builtin_amdgcn_rcpf(x);
}

// Elementwise core: x -> pre-normalization output value.
// m1 = mean(data), k1 = iscale/std(data)
__device__ __forceinline__ float lnon_elem(float x, float m1, float k1) {
    float d  = (x - m1) * k1;
    // theta = -pi + 2*pi*sigmoid(d)
    float sg = fast_rcp(1.0f + __expf(-d));
    float theta = fmaf(6.2831853071795864f, sg, -3.1415926535897932f);
    // ds = e * tanh(|d|)   (tanh(|d|) == |tanh(d)|, and is >= 0)
    float ax = fabsf(d);
    float t  = 1.0f - 2.0f * fast_rcp(__expf(2.0f * ax) + 1.0f);
    float dsv = 2.7182818284590452f * t;
    float sn = __sinf(theta);
    float cs = __cosf(theta);
    float dy = dsv * sn;
    float dx = dsv * cs;
    return fmaf(d, __expf(dy), dx);
}

// Two-value block reduction (sum, sumsq in double) + one atomicAdd pair per block.
__device__ __forceinline__ void block_reduce_add2(double s, double ss,
                                                  double* out0, double* out1) {
    #pragma unroll
    for (int off = 32; off > 0; off >>= 1) {
        s  += __shfl_down(s, off);
        ss += __shfl_down(ss, off);
    }
    __shared__ double lds[8][2];
    const int wave = threadIdx.x >> 6;
    const int lane = threadIdx.x & 63;
    if (lane == 0) { lds[wave][0] = s; lds[wave][1] = ss; }
    __syncthreads();
    if (threadIdx.x == 0) {
        const int nw = blockDim.x >> 6;
        double a = 0.0, b = 0.0;
        for (int i = 0; i < nw; ++i) { a += lds[i][0]; b += lds[i][1]; }
        atomicAdd(out0, a);
        atomicAdd(out1, b);
    }
}

__global__ void k_init(double* acc) {
    if (threadIdx.x < 4) acc[threadIdx.x] = 0.0;
}

// Pass 1: sum / sumsq of raw data.
__global__ void k_stats1(const float4* __restrict__ in, double* acc) {
    double s = 0.0, ss = 0.0;
    const int stride = gridDim.x * blockDim.x;
    for (int i = blockIdx.x * blockDim.x + threadIdx.x; i < NV; i += stride) {
        float4 v = in[i];
        s  += (double)v.x + (double)v.y + (double)v.z + (double)v.w;
        ss += (double)v.x * v.x + (double)v.y * v.y
            + (double)v.z * v.z + (double)v.w * v.w;
    }
    block_reduce_add2(s, ss, &acc[0], &acc[1]);
}

// Pass 2: compute pre-output elementwise, accumulate its sum / sumsq.
__global__ void k_stats2(const float4* __restrict__ in,
                         const float* __restrict__ iscale,
                         double* acc) {
    const double Nd  = (double)NTOT;
    const double s1  = acc[0];
    const double ss1 = acc[1];
    const double mean = s1 / Nd;
    const double var  = (ss1 - s1 * s1 / Nd) / (Nd - 1.0);
    const float  m1 = (float)mean;
    const float  k1 = (float)(1.0 / sqrt(var)) * iscale[0];

    double s = 0.0, ss = 0.0;
    const int stride = gridDim.x * blockDim.x;
    for (int i = blockIdx.x * blockDim.x + threadIdx.x; i < NV; i += stride) {
        float4 v = in[i];
        float p0 = lnon_elem(v.x, m1, k1);
        float p1 = lnon_elem(v.y, m1, k1);
        float p2 = lnon_elem(v.z, m1, k1);
        float p3 = lnon_elem(v.w, m1, k1);
        s  += (double)p0 + (double)p1 + (double)p2 + (double)p3;
        ss += (double)p0 * p0 + (double)p1 * p1
            + (double)p2 * p2 + (double)p3 * p3;
    }
    block_reduce_add2(s, ss, &acc[2], &acc[3]);
}

// Pass 3: recompute pre-output, normalize with pass-2 stats, scale, store.
__global__ void k_final(const float4* __restrict__ in,
                        const float* __restrict__ iscale,
                        const float* __restrict__ oscale,
                        const double* __restrict__ acc,
                        float4* __restrict__ out) {
    const double Nd  = (double)NTOT;
    const double s1  = acc[0];
    const double ss1 = acc[1];
    const double mean1 = s1 / Nd;
    const double var1  = (ss1 - s1 * s1 / Nd) / (Nd - 1.0);
    const float  m1 = (float)mean1;
    const float  k1 = (float)(1.0 / sqrt(var1)) * iscale[0];

    const double s2  = acc[2];
    const double ss2 = acc[3];
    const double mean2 = s2 / Nd;
    const double var2  = (ss2 - s2 * s2 / Nd) / (Nd - 1.0);
    const float  m2 = (float)mean2;
    const float  k2 = (float)(1.0 / sqrt(var2)) * oscale[0];

    const int stride = gridDim.x * blockDim.x;
    for (int i = blockIdx.x * blockDim.x + threadIdx.x; i < NV; i += stride) {
        float4 v = in[i];
        float4 o;
        o.x = (lnon_elem(v.x, m1, k1) - m2) * k2;
        o.y = (lnon_elem(v.y, m1, k1) - m2) * k2;
        o.z = (lnon_elem(v.z, m1, k1) - m2) * k2;
        o.w = (lnon_elem(v.w, m1, k1) - m2) * k2;
        out[i] = o;
    }
}

extern "C" void kernel_launch(void* const* d_in, const int* in_sizes, int n_in,
                              void* d_out, int out_size, void* d_ws, size_t ws_size,
                              hipStream_t stream) {
    const float4* data   = (const float4*)d_in[0];
    const float*  iscale = (const float*)d_in[1];
    const float*  oscale = (const float*)d_in[2];
    // d_in[3..6] (weight_sp, weight_ch, conv_w, conv_b) are mathematically
    // irrelevant: softmax row-sums are identically 1.
    float4* out = (float4*)d_out;
    double* acc = (double*)d_ws;   // acc[0..3] = sum1, sumsq1, sum2, sumsq2

    const dim3 grid(2048), block(256);
    hipLaunchKernelGGL(k_init,   dim3(1), dim3(64), 0, stream, acc);
    hipLaunchKernelGGL(k_stats1, grid, block, 0, stream, data, acc);
    hipLaunchKernelGGL(k_stats2, grid, block, 0, stream, data, iscale, acc);
    hipLaunchKernelGGL(k_final,  grid, block, 0, stream, data, iscale, oscale, acc, out);
}

// Round 2
// 114.135 us; speedup vs baseline: 1.7862x; 1.7862x over previous
//
#include <hip/hip_runtime.h>
#include <math.h>

// Problem: B=16, C=128, H=W=64 -> N = 8,388,608 f32 elements.
// Reference collapses analytically:
//   softmax(w).sum(axis=1) == 1   =>  integral(d, param, idx) == param[idx]
//   linspace tables are affine    =>  interplot == a + b*index
//   theta = -pi + 2*pi*sigmoid(d) =>  sin(theta) = -sin(2*pi*sg), cos likewise
//   ds    = e * |tanh(d)| = e * tanh(|d|)
//   pre   = d*exp(ds*sin(theta)) + ds*cos(theta)
// Global mean/std (ddof=1) normalize of input (x iscale) and of pre (x oscale).
//
// Round-1 lesson: f64 atomicAdd compiles to a CAS loop -> 2048-way same-address
// contention tail dominated (57us/pass @ 2% VALUBusy). This version uses
// per-block partials in d_ws + redundant per-block reduction in the consumer
// kernel's prologue. No atomics anywhere, 3 launches total.

#define NTOT 8388608
#define NV   (NTOT / 4)          // 2,097,152 float4
#define GA   1024                // blocks for every kernel (compile-time)
#define TB   256                 // threads per block
#define STRIDE (GA * TB)         // 262,144 threads total
#define ITERS  (NV / STRIDE)     // 8 float4 per thread, fully unrolled

__device__ __forceinline__ float fast_rcp(float x) {
    return __builtin_amdgcn_rcpf(x);
}

// x -> pre-normalization output value. m1 = mean(data), k1 = iscale/std(data).
// 2 x v_exp + 1 x v_sin + 1 x v_cos + 2 x v_rcp per element.
__device__ __forceinline__ float lnon_elem(float x, float m1, float k1) {
    float d  = (x - m1) * k1;
    float a  = fminf(fabsf(d), 30.0f);       // saturation guard (exact past ~17)
    float Ea = __expf(a);                    // e^{|d|}, shared by sigmoid & tanh
    float sg = (d >= 0.0f ? Ea : 1.0f) * fast_rcp(1.0f + Ea);   // sigmoid(d)
    float t  = 1.0f - 2.0f * fast_rcp(1.0f + Ea * Ea);          // tanh(|d|) >= 0
    float dsv = 2.71828182845904523f * t;                       // ds
    // theta = 2*pi*sg - pi; v_sin_f32 input is in REVOLUTIONS: sin(2*pi*sg).
    float sn = -__builtin_amdgcn_sinf(sg);   // sin(theta)
    float cs = -__builtin_amdgcn_cosf(sg);   // cos(theta)
    return fmaf(d, __expf(dsv * sn), dsv * cs);
}

// Reduce 4 doubles across the 256-thread block; result valid in ALL threads.
__device__ __forceinline__ void block_reduce4(double& s1, double& q1,
                                              double& s2, double& q2) {
    #pragma unroll
    for (int off = 32; off > 0; off >>= 1) {
        s1 += __shfl_down(s1, off);
        q1 += __shfl_down(q1, off);
        s2 += __shfl_down(s2, off);
        q2 += __shfl_down(q2, off);
    }
    __shared__ double lds[4][4];
    const int wave = threadIdx.x >> 6;
    const int lane = threadIdx.x & 63;
    __syncthreads();                          // guard LDS reuse across calls
    if (lane == 0) {
        lds[wave][0] = s1; lds[wave][1] = q1;
        lds[wave][2] = s2; lds[wave][3] = q2;
    }
    __syncthreads();
    s1 = lds[0][0] + lds[1][0] + lds[2][0] + lds[3][0];
    q1 = lds[0][1] + lds[1][1] + lds[2][1] + lds[3][1];
    s2 = lds[0][2] + lds[1][2] + lds[2][2] + lds[3][2];
    q2 = lds[0][3] + lds[1][3] + lds[2][3] + lds[3][3];
}

// Pass 1: per-block {sum, sumsq} of raw data -> P1[blockIdx].
__global__ __launch_bounds__(TB) void k_p1(const float4* __restrict__ in,
                                           double2* __restrict__ P1) {
    const int t = blockIdx.x * TB + threadIdx.x;
    float s = 0.0f, q = 0.0f;
    #pragma unroll
    for (int k = 0; k < ITERS; ++k) {
        float4 v = in[t + k * STRIDE];
        s += v.x + v.y + v.z + v.w;
        q += v.x * v.x + v.y * v.y + v.z * v.z + v.w * v.w;
    }
    double s1 = (double)s, q1 = (double)q, z2 = 0.0, z3 = 0.0;
    block_reduce4(s1, q1, z2, z3);
    if (threadIdx.x == 0) P1[blockIdx.x] = make_double2(s1, q1);
}

// Derive (mean, scale) from a {sum, sumsq} pair.
__device__ __forceinline__ void stats_from(double s, double q, float sc,
                                           float& m, float& k) {
    const double Nd = (double)NTOT;
    double mean = s / Nd;
    double var  = (q - s * s / Nd) / (Nd - 1.0);
    m = (float)mean;
    k = (float)(1.0 / sqrt(var)) * sc;
}

// Pass 2: redundant reduce of P1 -> (m1,k1); elementwise pre-output stats
// -> P2[blockIdx].
__global__ __launch_bounds__(TB) void k_p2(const float4* __restrict__ in,
                                           const float* __restrict__ iscale,
                                           const double2* __restrict__ P1,
                                           double2* __restrict__ P2) {
    double s1 = 0.0, q1 = 0.0, s2 = 0.0, q2 = 0.0;
    #pragma unroll
    for (int i = threadIdx.x; i < GA; i += TB) {
        double2 p = P1[i];
        s1 += p.x; q1 += p.y;
    }
    block_reduce4(s1, q1, s2, q2);
    float m1, k1;
    stats_from(s1, q1, iscale[0], m1, k1);

    const int t = blockIdx.x * TB + threadIdx.x;
    float s = 0.0f, q = 0.0f;
    #pragma unroll
    for (int k = 0; k < ITERS; ++k) {
        float4 v = in[t + k * STRIDE];
        float p0 = lnon_elem(v.x, m1, k1);
        float p1 = lnon_elem(v.y, m1, k1);
        float p2 = lnon_elem(v.z, m1, k1);
        float p3 = lnon_elem(v.w, m1, k1);
        s += p0 + p1 + p2 + p3;
        q += p0 * p0 + p1 * p1 + p2 * p2 + p3 * p3;
    }
    double a = (double)s, b = (double)q, z2 = 0.0, z3 = 0.0;
    block_reduce4(a, b, z2, z3);
    if (threadIdx.x == 0) P2[blockIdx.x] = make_double2(a, b);
}

// Pass 3: redundant reduce of P1+P2 -> all constants; elementwise + store.
__global__ __launch_bounds__(TB) void k_p3(const float4* __restrict__ in,
                                           const float* __restrict__ iscale,
                                           const float* __restrict__ oscale,
                                           const double2* __restrict__ P1,
                                           const double2* __restrict__ P2,
                                           float4* __restrict__ out) {
    double s1 = 0.0, q1 = 0.0, s2 = 0.0, q2 = 0.0;
    #pragma unroll
    for (int i = threadIdx.x; i < GA; i += TB) {
        double2 p = P1[i];
        double2 r = P2[i];
        s1 += p.x; q1 += p.y;
        s2 += r.x; q2 += r.y;
    }
    block_reduce4(s1, q1, s2, q2);
    float m1, k1, m2, k2;
    stats_from(s1, q1, iscale[0], m1, k1);
    stats_from(s2, q2, oscale[0], m2, k2);

    const int t = blockIdx.x * TB + threadIdx.x;
    #pragma unroll
    for (int k = 0; k < ITERS; ++k) {
        float4 v = in[t + k * STRIDE];
        float4 o;
        o.x = (lnon_elem(v.x, m1, k1) - m2) * k2;
        o.y = (lnon_elem(v.y, m1, k1) - m2) * k2;
        o.z = (lnon_elem(v.z, m1, k1) - m2) * k2;
        o.w = (lnon_elem(v.w, m1, k1) - m2) * k2;
        out[t + k * STRIDE] = o;
    }
}

extern "C" void kernel_launch(void* const* d_in, const int* in_sizes, int n_in,
                              void* d_out, int out_size, void* d_ws, size_t ws_size,
                              hipStream_t stream) {
    const float4* data   = (const float4*)d_in[0];
    const float*  iscale = (const float*)d_in[1];
    const float*  oscale = (const float*)d_in[2];
    // d_in[3..6] (weight_sp, weight_ch, conv_w, conv_b): mathematically dead
    // (softmax row-sums are identically 1).
    float4* out = (float4*)d_out;
    double2* P1 = (double2*)d_ws;          // GA entries
    double2* P2 = P1 + GA;                 // GA entries (32 KiB total)

    hipLaunchKernelGGL(k_p1, dim3(GA), dim3(TB), 0, stream, data, P1);
    hipLaunchKernelGGL(k_p2, dim3(GA), dim3(TB), 0, stream, data, iscale, P1, P2);
    hipLaunchKernelGGL(k_p3, dim3(GA), dim3(TB), 0, stream, data, iscale, oscale,
                       P1, P2, out);
}